// Round 2
// baseline (176.998 us; speedup 1.0000x reference)
//
#include <hip/hip_runtime.h>
#include <hip/hip_bf16.h>
#include <cstddef>
#include <cstdint>

typedef __attribute__((ext_vector_type(8))) short short8_t;   // 8 bf16 (4 VGPRs)
typedef __attribute__((ext_vector_type(4))) float f32x4;
typedef __attribute__((ext_vector_type(2))) float f32x2;
typedef unsigned short ushort4a __attribute__((ext_vector_type(4))); // 8B

// Per-wave fence: forbid compiler motion of LDS ops and drain lgkm queue.
// Cross-lane LDS deps are invisible to per-thread dependence analysis.
#define WAVE_FENCE()                                        \
  do {                                                      \
    asm volatile("s_waitcnt lgkmcnt(0)" ::: "memory");      \
    __builtin_amdgcn_sched_barrier(0);                      \
  } while (0)

namespace {
constexpr int T = 2048;
constexpr int NB = 16;
constexpr int NJ = 53;
constexpr int NN = 18;              // names
constexpr int TTILE = 128;          // R13: L2-resident x-column footprint
constexpr int NTILES = T / TTILE;   // 16
constexpr int MT_LIN = 9;           // ceil(130/16) m-tiles for linear phase
constexpr int MT_CNV = 8;           // conv m-tiles
constexpr int HROWS = TTILE + 2;    // 130 h rows actually consumed by conv
constexpr int HSTR = 36;            // ushort stride per h row (72B, 8B-aligned rows)
// R14: SSTR 40->38. 40 gave g-stride 160 dwords == 0 mod 32 -> every staging
// write was a 4-way bank conflict (~2.6M of the 3.47M conflict cycles).
// 38: 4*38=152 == 24 mod 32 -> writes 2-way (free); reads split to 8B so odd
// rows stay aligned; read banks 6*row+4c all distinct -> 2-way (free).
constexpr int SSTR = 38;            // f32 stride of store-staging tile (152B)
constexpr int NBLK = NB * NJ * NTILES;  // 13568
constexpr int XSPAN = NBLK / 8;         // 1696 (bijective XCD swizzle)
}

__constant__ int c_name_ids[NJ] = {
    0,1,2,3,4,1,2,3,4,5,6,7,8,9,10,11,12,13,14,15,16,14,15,16,14,15,16,
    14,15,16,14,15,16,10,11,12,13,14,15,16,14,15,16,14,15,16,14,15,16,
    14,15,16,17};

// Precomputed weight fragments: [name][ks|k][nt][hi/lo][lane]
__device__ short8_t g_linfrag[NN][2][2][2][64];   // 147 KB
__device__ short8_t g_convfrag[NN][3][2][2][64];  // 221 KB

__device__ __forceinline__ unsigned short f2bf(float f) {
  return __builtin_bit_cast(unsigned short, __float2bfloat16(f));
}
__device__ __forceinline__ float bf2f(unsigned short u) {
  return __bfloat162float(__builtin_bit_cast(__hip_bfloat16, u));
}

// slot map: slot(g,e) -> k = 4g + (e&3) + 16*(e>>2); used identically for A and B
// fragments, so any true HW k-map yields a correct dot product.

__global__ __launch_bounds__(64)
void prep_weights(const float* __restrict__ lin_w,
                  const float* __restrict__ conv_w)
{
  const int n = blockIdx.x;
  const int l = threadIdx.x;
  const int r = l & 15;
  const int g = l >> 4;
#pragma unroll
  for (int ks = 0; ks < 2; ++ks)
#pragma unroll
    for (int nt = 0; nt < 2; ++nt) {
      short8_t hi8, lo8;
#pragma unroll
      for (int e = 0; e < 8; ++e) {
        const int kk = 4 * g + (e & 3) + 16 * (e >> 2);
        const float w = lin_w[((size_t)n * 64 + ks * 32 + kk) * 32 + r + 16 * nt];
        const unsigned short h = f2bf(w);
        hi8[e] = (short)h;
        lo8[e] = (short)f2bf(w - bf2f(h));
      }
      g_linfrag[n][ks][nt][0][l] = hi8;
      g_linfrag[n][ks][nt][1][l] = lo8;
    }
#pragma unroll
  for (int k = 0; k < 3; ++k)
#pragma unroll
    for (int nt = 0; nt < 2; ++nt) {
      short8_t hi8, lo8;
#pragma unroll
      for (int e = 0; e < 8; ++e) {
        const int i = 4 * g + (e & 3) + 16 * (e >> 2);
        const float w = conv_w[(((size_t)n * 32 + r + 16 * nt) * 32 + i) * 3 + k];
        const unsigned short h = f2bf(w);
        hi8[e] = (short)h;
        lo8[e] = (short)f2bf(w - bf2f(h));
      }
      g_convfrag[n][k][nt][0][l] = hi8;
      g_convfrag[n][k][nt][1][l] = lo8;
    }
}

// R14 structure: lin-phase A-fragments are loaded DIRECTLY global->VGPR.
// Lane (g,r)'s fragment is rows t(r), cols [4g,4g+4) and [16+4g,16+4g+4) of
// x[j] / x[j-1] -- two coalesced f32x4 loads per source column (4 lanes x 16B
// = 64B segments; chunk pairs cover full 128B lines, L2 merges). This deletes
// the LDS-DMA + XOR-swizzle + per-iteration vmcnt(0) drain entirely: loads
// get per-use waits the compiler can schedule, and LDS drops to 19.1KB ->
// up to 8 blocks/CU (was 6).
// hi/lo split is RTZ: hi = top16(f), lo = f - hi (exact) -> 2 fewer VALU
// ops/elem than the RNE round-trip; dropped al*bll term unchanged (~2^-16).
__global__ __launch_bounds__(256, 7)
void fused_rcb_mfma(const float* __restrict__ x,
                    const float* __restrict__ lin_b,
                    const float* __restrict__ conv_b,
                    float* __restrict__ out)
{
  __shared__ __align__(16) unsigned short s_hi[HROWS * HSTR];  // 9.36 KB
  __shared__ __align__(16) float s_st[4][16 * SSTR];           // 9.73 KB

  const int raw = blockIdx.x;
  const int bid = (raw % 8) * XSPAN + (raw / 8);   // bijective XCD swizzle
  const int j    = bid % NJ;
  const int tile = (bid / NJ) % NTILES;
  const int b    = bid / (NJ * NTILES);
  const int nid  = c_name_ids[j];
  const int jp   = (j > 0) ? (j - 1) : 0;
  const int t0   = tile * TTILE;

  const int tid = threadIdx.x;
  const int wv = tid >> 6;        // wave 0..3
  const int l  = tid & 63;
  const int r  = l & 15;          // M/N index within fragment
  const int g  = l >> 4;          // k-slot group

  const float* xj_base = x + ((size_t)b * T * NJ + j) * 32;
  const float* xp_base = x + ((size_t)b * T * NJ + jp) * 32;

  // ---- linear weight fragments: coalesced 16B/lane loads from prep table ----
  short8_t blh[2][2], bll[2][2];
#pragma unroll
  for (int ks = 0; ks < 2; ++ks)
#pragma unroll
    for (int nt = 0; nt < 2; ++nt) {
      blh[ks][nt] = g_linfrag[nid][ks][nt][0][l];
      bll[ks][nt] = g_linfrag[nid][ks][nt][1][l];
    }
  const float lb0 = lin_b[nid * 32 + r];
  const float lb1 = lin_b[nid * 32 + r + 16];

  // ---------------- linear phase: h = relu(feat @ W + b) ----------------
  for (int mt = wv; mt < MT_LIN; mt += 4) {
    // Lane's A-row time index, reflect-padded.
    int t = t0 + mt * 16 + r - 1;
    t = (t < 0) ? -t : t;
    t = (t > T - 1) ? (2 * (T - 1) - t) : t;
    const float* rowj = xj_base + (size_t)t * (NJ * 32);
    const float* rowp = xp_base + (size_t)t * (NJ * 32);
    f32x4 v00 = *reinterpret_cast<const f32x4*>(rowj + 4 * g);
    f32x4 v01 = *reinterpret_cast<const f32x4*>(rowj + 16 + 4 * g);
    f32x4 v10 = *reinterpret_cast<const f32x4*>(rowp + 4 * g);
    f32x4 v11 = *reinterpret_cast<const f32x4*>(rowp + 16 + 4 * g);

    short8_t ah[2], al[2];
#pragma unroll
    for (int ks = 0; ks < 2; ++ks) {
      const f32x4 a0 = ks ? v10 : v00;
      const f32x4 a1 = ks ? v11 : v01;
#pragma unroll
      for (int e = 0; e < 8; ++e) {
        const float f = (e < 4) ? a0[e] : a1[e - 4];
        const uint32_t bi = __builtin_bit_cast(uint32_t, f);
        ah[ks][e] = (short)(unsigned short)(bi >> 16);                  // hi = RTZ top16
        const float lo = f - __builtin_bit_cast(float, bi & 0xffff0000u); // exact
        al[ks][e] = (short)f2bf(lo);
      }
    }

#pragma unroll
    for (int nt = 0; nt < 2; ++nt) {
      const float lb = nt ? lb1 : lb0;
      f32x4 acc = {lb, lb, lb, lb};
#pragma unroll
      for (int ks = 0; ks < 2; ++ks) {
        acc = __builtin_amdgcn_mfma_f32_16x16x32_bf16(ah[ks], blh[ks][nt], acc, 0, 0, 0);
        acc = __builtin_amdgcn_mfma_f32_16x16x32_bf16(al[ks], blh[ks][nt], acc, 0, 0, 0);
        acc = __builtin_amdgcn_mfma_f32_16x16x32_bf16(ah[ks], bll[ks][nt], acc, 0, 0, 0);
      }
      // C/D layout (m89): row = 4g+q, col = r
#pragma unroll
      for (int q = 0; q < 4; ++q) {
        const int hrow = mt * 16 + 4 * g + q;
        if (hrow < HROWS)   // only mt=8 tail rows are out of range
          s_hi[hrow * HSTR + r + 16 * nt] = f2bf(fmaxf(acc[q], 0.0f));
      }
    }
  }
  __syncthreads();

  // ---- conv weight fragments (loaded post-barrier to shorten live range) ----
  short8_t bch[3][2], bcl[3][2];
#pragma unroll
  for (int k = 0; k < 3; ++k)
#pragma unroll
    for (int nt = 0; nt < 2; ++nt) {
      bch[k][nt] = g_convfrag[nid][k][nt][0][l];
      bcl[k][nt] = g_convfrag[nid][k][nt][1][l];
    }
  const float cb0 = conv_b[nid * 32 + r];
  const float cb1 = conv_b[nid * 32 + r + 16];

  float* st = s_st[wv];           // wave-private staging

  // ---------------- conv phase: y[t] = sum_k h[t+k-1] @ cw[k] + cb ----------------
  for (int mt = wv; mt < MT_CNV; mt += 4) {
    const int m0 = mt * 16;
    short8_t ah[3];
#pragma unroll
    for (int k = 0; k < 3; ++k) {
      const int arow = m0 + r + k;
      const ushort4a u0 = *reinterpret_cast<const ushort4a*>(&s_hi[arow * HSTR + 4 * g]);
      const ushort4a u1 = *reinterpret_cast<const ushort4a*>(&s_hi[arow * HSTR + 16 + 4 * g]);
      short8_t hi8;
#pragma unroll
      for (int e = 0; e < 4; ++e) {
        hi8[e] = (short)u0[e];
        hi8[e + 4] = (short)u1[e];
      }
      ah[k] = hi8;
    }

    f32x4 accv[2];
#pragma unroll
    for (int nt = 0; nt < 2; ++nt) {
      const float cb = nt ? cb1 : cb0;
      f32x4 acc = {cb, cb, cb, cb};
#pragma unroll
      for (int k = 0; k < 3; ++k) {
        acc = __builtin_amdgcn_mfma_f32_16x16x32_bf16(ah[k], bch[k][nt], acc, 0, 0, 0);
        acc = __builtin_amdgcn_mfma_f32_16x16x32_bf16(ah[k], bcl[k][nt], acc, 0, 0, 0);
      }
      accv[nt] = acc;
    }

    // ---- wide-store epilogue: transpose acc through wave-private LDS ----
    WAVE_FENCE();   // WAR: previous m-tile's staging reads retired
#pragma unroll
    for (int nt = 0; nt < 2; ++nt)
#pragma unroll
      for (int q = 0; q < 4; ++q)
        st[(4 * g + q) * SSTR + r + 16 * nt] = accv[nt][q];
    WAVE_FENCE();   // RAW: staging writes visible to transposed reads

#pragma unroll
    for (int h2 = 0; h2 < 2; ++h2) {
      const int row = h2 * 8 + (l >> 3);          // 8-lane groups read one row
      const float* rp = st + row * SSTR + (l & 7) * 4;
      const f32x2 rd0 = *reinterpret_cast<const f32x2*>(rp);      // 8B reads keep
      const f32x2 rd1 = *reinterpret_cast<const f32x2*>(rp + 2);  // odd rows aligned
      f32x4 rd;
      rd[0] = rd0[0]; rd[1] = rd0[1]; rd[2] = rd1[0]; rd[3] = rd1[1];
      const int t = t0 + m0 + row;
      // Nontemporal: out is write-once; do not evict the L2-resident x columns.
      __builtin_nontemporal_store(rd, reinterpret_cast<f32x4*>(
          out + ((size_t)(b * T + t) * NJ + j) * 32 + (l & 7) * 4));
    }
  }
}

extern "C" void kernel_launch(void* const* d_in, const int* in_sizes, int n_in,
                              void* d_out, int out_size, void* d_ws, size_t ws_size,
                              hipStream_t stream) {
  const float* x      = (const float*)d_in[0];
  const float* lin_w  = (const float*)d_in[1];
  const float* lin_b  = (const float*)d_in[2];
  const float* conv_w = (const float*)d_in[3];
  const float* conv_b = (const float*)d_in[4];
  float* out = (float*)d_out;

  prep_weights<<<dim3(NN), 64, 0, stream>>>(lin_w, conv_w);
  fused_rcb_mfma<<<dim3(NBLK), 256, 0, stream>>>(x, lin_b, conv_b, out);
}

// Round 3
// 89.194 us; speedup vs baseline: 1.9844x; 1.9844x over previous
//
#include <hip/hip_runtime.h>
#include <hip/hip_bf16.h>
#include <cstddef>
#include <cstdint>

typedef __attribute__((ext_vector_type(8))) short short8_t;   // 8 bf16 (4 VGPRs)
typedef __attribute__((ext_vector_type(4))) float f32x4;
typedef __attribute__((ext_vector_type(2))) float f32x2;
typedef unsigned short ushort4a __attribute__((ext_vector_type(4))); // 8B

// Per-wave fences (R10/R12-proven): forbid compiler motion of memory ops and
// drain the relevant HW queue. Cross-lane LDS deps and LDS-DMA writes are
// invisible to per-thread dependence analysis.
#define WAVE_FENCE()                                        \
  do {                                                      \
    asm volatile("s_waitcnt lgkmcnt(0)" ::: "memory");      \
    __builtin_amdgcn_sched_barrier(0);                      \
  } while (0)
#define VM_FENCE()                                          \
  do {                                                      \
    asm volatile("s_waitcnt vmcnt(0)" ::: "memory");        \
    __builtin_amdgcn_sched_barrier(0);                      \
  } while (0)

namespace {
constexpr int T = 2048;
constexpr int NB = 16;
constexpr int NJ = 53;
constexpr int NN = 18;              // names
constexpr int TTILE = 128;          // R13: L2-resident x-column footprint
constexpr int NTILES = T / TTILE;   // 16
constexpr int MT_LIN = 9;           // ceil(130/16) m-tiles for linear phase
constexpr int MT_CNV = 8;           // conv m-tiles
constexpr int HROWS = TTILE + 2;    // 130 h rows actually consumed by conv
constexpr int HSTR = 36;            // ushort stride per h row (72B, 8B-aligned rows)
// R15: SSTR=38 (from R14 analysis). SSTR=40 gave g-stride 160 dwords == 0
// mod 32 -> every staging write 4-way conflicted (~2.6M of R13's 3.47M
// conflict cycles). 152 == 24 mod 32 -> writes 2-way (free). Reads split to
// 8B so odd rows stay aligned.
constexpr int SSTR = 38;            // f32 stride of store-staging tile (152B)
constexpr int NBLK = NB * NJ * NTILES;  // 13568
constexpr int XSPAN = NBLK / 8;         // 1696 (bijective XCD swizzle)
}

__constant__ int c_name_ids[NJ] = {
    0,1,2,3,4,1,2,3,4,5,6,7,8,9,10,11,12,13,14,15,16,14,15,16,14,15,16,
    14,15,16,14,15,16,10,11,12,13,14,15,16,14,15,16,14,15,16,14,15,16,
    14,15,16,17};

// Precomputed weight fragments: [name][ks|k][nt][hi/lo][lane]
__device__ short8_t g_linfrag[NN][2][2][2][64];   // 147 KB
__device__ short8_t g_convfrag[NN][3][2][2][64];  // 221 KB

__device__ __forceinline__ unsigned short f2bf(float f) {
  return __builtin_bit_cast(unsigned short, __float2bfloat16(f));
}
__device__ __forceinline__ float bf2f(unsigned short u) {
  return __bfloat162float(__builtin_bit_cast(__hip_bfloat16, u));
}

// slot map: slot(g,e) -> k = 4g + (e&3) + 16*(e>>2); used identically for A and B
// fragments, so any true HW k-map yields a correct dot product.

__global__ __launch_bounds__(64)
void prep_weights(const float* __restrict__ lin_w,
                  const float* __restrict__ conv_w)
{
  const int n = blockIdx.x;
  const int l = threadIdx.x;
  const int r = l & 15;
  const int g = l >> 4;
#pragma unroll
  for (int ks = 0; ks < 2; ++ks)
#pragma unroll
    for (int nt = 0; nt < 2; ++nt) {
      short8_t hi8, lo8;
#pragma unroll
      for (int e = 0; e < 8; ++e) {
        const int kk = 4 * g + (e & 3) + 16 * (e >> 2);
        const float w = lin_w[((size_t)n * 64 + ks * 32 + kk) * 32 + r + 16 * nt];
        const unsigned short h = f2bf(w);
        hi8[e] = (short)h;
        lo8[e] = (short)f2bf(w - bf2f(h));
      }
      g_linfrag[n][ks][nt][0][l] = hi8;
      g_linfrag[n][ks][nt][1][l] = lo8;
    }
#pragma unroll
  for (int k = 0; k < 3; ++k)
#pragma unroll
    for (int nt = 0; nt < 2; ++nt) {
      short8_t hi8, lo8;
#pragma unroll
      for (int e = 0; e < 8; ++e) {
        const int i = 4 * g + (e & 3) + 16 * (e >> 2);
        const float w = conv_w[(((size_t)n * 32 + r + 16 * nt) * 32 + i) * 3 + k];
        const unsigned short h = f2bf(w);
        hi8[e] = (short)h;
        lo8[e] = (short)f2bf(w - bf2f(h));
      }
      g_convfrag[n][k][nt][0][l] = hi8;
      g_convfrag[n][k][nt][1][l] = lo8;
    }
}

// R15 = R13 structure (LDS-DMA staging, launch_bounds(256,4) -- R14's (256,7)
// caused VGPR=36 + scratch spills, +263MB HBM writes) with:
//   - SSTR=38 staging bank fix
//   - RTZ hi/lo split (bit-ops only) in the hot cvt loop
//   - DMA issue moved directly after fragment ds_reads retire (cvt after)
//   - conv-weight fragment loads hoisted before __syncthreads (latency hides
//     under the barrier wait)
//   - s_hi trimmed to the 130 rows conv actually reads
__global__ __launch_bounds__(256, 4)
void fused_rcb_mfma(const float* __restrict__ x,
                    const float* __restrict__ lin_b,
                    const float* __restrict__ conv_b,
                    float* __restrict__ out)
{
  __shared__ __align__(16) unsigned short s_hi[HROWS * HSTR];  // 9.36 KB
  __shared__ __align__(16) char s_feat[4][4096];               // 16 KB: feat stage (lin) / store stage (conv)

  const int raw = blockIdx.x;
  const int bid = (raw % 8) * XSPAN + (raw / 8);   // bijective XCD swizzle
  const int j    = bid % NJ;
  const int tile = (bid / NJ) % NTILES;
  const int b    = bid / (NJ * NTILES);
  const int nid  = c_name_ids[j];
  const int jp   = (j > 0) ? (j - 1) : 0;
  const int t0   = tile * TTILE;

  const int tid = threadIdx.x;
  const int wv = tid >> 6;        // wave 0..3
  const int l  = tid & 63;
  const int r  = l & 15;          // M/N index within fragment
  const int g  = l >> 4;          // k-slot group

  char* featc = s_feat[wv];       // wave-private

  const float* xj_base = x + ((size_t)b * T * NJ + j) * 32;
  const float* xp_base = x + ((size_t)b * T * NJ + jp) * 32;

  // ---- linear weight fragments: coalesced 16B/lane loads from prep table ----
  short8_t blh[2][2], bll[2][2];
#pragma unroll
  for (int ks = 0; ks < 2; ++ks)
#pragma unroll
    for (int nt = 0; nt < 2; ++nt) {
      blh[ks][nt] = g_linfrag[nid][ks][nt][0][l];
      bll[ks][nt] = g_linfrag[nid][ks][nt][1][l];
    }
  const float lb0 = lin_b[nid * 32 + r];
  const float lb1 = lin_b[nid * 32 + r + 16];

  // Issue the 4 LDS-DMA loads for m-tile mt: 2 j x 2 groups of 8 rows, each
  // instruction a contiguous 1KB (8 full lines). Global source byte is
  // inverse-XOR-swizzled so LDS holds the swizzled layout (rule #21).
  auto issue_feat = [&](int mt) {
#pragma unroll
    for (int j2 = 0; j2 < 2; ++j2) {
      const float* jb = j2 ? xp_base : xj_base;
#pragma unroll
      for (int i = 0; i < 2; ++i) {
        const int row = i * 8 + (l >> 3);
        int t = t0 + mt * 16 + row - 1;       // reflect padding in time
        if (t < 0) t = -t;
        if (t > T - 1) t = 2 * (T - 1) - t;
        const char* src = reinterpret_cast<const char*>(jb + (size_t)t * (NJ * 32))
                          + (((l & 7) * 16) ^ ((row & 7) << 4));
        __builtin_amdgcn_global_load_lds(
            (const __attribute__((address_space(1))) unsigned int*)src,
            (__attribute__((address_space(3))) unsigned int*)(&s_feat[wv][j2 * 2048 + i * 1024]),
            16, 0, 0);
      }
    }
  };

  // ---------------- linear phase: h = relu(feat @ W + b) ----------------
  issue_feat(wv);
  for (int mt = wv; mt < MT_LIN; mt += 4) {
    VM_FENCE();   // feat[mt] fully landed in LDS (LDS-DMA tracked by vmcnt)

    // Fragment ds_reads first; cvt deferred until after next DMA is issued so
    // the DMA overlaps the cvt chain AND the MFMA block.
    f32x4 a0[2], a1[2];
#pragma unroll
    for (int ks = 0; ks < 2; ++ks) {
      const char* fw = featc + ks * 2048 + r * 128;
      a0[ks] = *reinterpret_cast<const f32x4*>(fw + ((16 * g) ^ ((r & 7) << 4)));
      a1[ks] = *reinterpret_cast<const f32x4*>(fw + ((64 + 16 * g) ^ ((r & 7) << 4)));
    }
    WAVE_FENCE();                       // feat reads retired -> buffer reusable
    if (mt + 4 < MT_LIN) issue_feat(mt + 4);   // DMA overlaps cvt + MFMA below

    short8_t ah[2], al[2];
#pragma unroll
    for (int ks = 0; ks < 2; ++ks) {
#pragma unroll
      for (int e = 0; e < 8; ++e) {
        const float f = (e < 4) ? a0[ks][e] : a1[ks][e - 4];
        const uint32_t bi = __builtin_bit_cast(uint32_t, f);
        ah[ks][e] = (short)(unsigned short)(bi >> 16);                    // hi = RTZ top16
        const float lo = f - __builtin_bit_cast(float, bi & 0xffff0000u); // exact residual
        al[ks][e] = (short)(unsigned short)(__builtin_bit_cast(uint32_t, lo) >> 16); // RTZ
      }
    }

#pragma unroll
    for (int nt = 0; nt < 2; ++nt) {
      const float lb = nt ? lb1 : lb0;
      f32x4 acc = {lb, lb, lb, lb};
#pragma unroll
      for (int ks = 0; ks < 2; ++ks) {
        acc = __builtin_amdgcn_mfma_f32_16x16x32_bf16(ah[ks], blh[ks][nt], acc, 0, 0, 0);
        acc = __builtin_amdgcn_mfma_f32_16x16x32_bf16(al[ks], blh[ks][nt], acc, 0, 0, 0);
        acc = __builtin_amdgcn_mfma_f32_16x16x32_bf16(ah[ks], bll[ks][nt], acc, 0, 0, 0);
      }
      // C/D layout (m89): row = 4g+q, col = r
#pragma unroll
      for (int q = 0; q < 4; ++q) {
        const int hrow = mt * 16 + 4 * g + q;
        if (hrow < HROWS)   // only mt=8 tail rows are out of range
          s_hi[hrow * HSTR + r + 16 * nt] = f2bf(fmaxf(acc[q], 0.0f));
      }
    }
  }

  // ---- conv weight fragments: issue BEFORE the barrier so the global-load
  // latency hides under the slowest wave's lin tail ----
  short8_t bch[3][2], bcl[3][2];
#pragma unroll
  for (int k = 0; k < 3; ++k)
#pragma unroll
    for (int nt = 0; nt < 2; ++nt) {
      bch[k][nt] = g_convfrag[nid][k][nt][0][l];
      bcl[k][nt] = g_convfrag[nid][k][nt][1][l];
    }
  const float cb0 = conv_b[nid * 32 + r];
  const float cb1 = conv_b[nid * 32 + r + 16];

  __syncthreads();

  float* st = reinterpret_cast<float*>(featc);   // alias: feat buffer dead in conv

  // ---------------- conv phase: y[t] = sum_k h[t+k-1] @ cw[k] + cb ----------------
  for (int mt = wv; mt < MT_CNV; mt += 4) {
    const int m0 = mt * 16;
    short8_t ah[3];
#pragma unroll
    for (int k = 0; k < 3; ++k) {
      const int arow = m0 + r + k;
      const ushort4a u0 = *reinterpret_cast<const ushort4a*>(&s_hi[arow * HSTR + 4 * g]);
      const ushort4a u1 = *reinterpret_cast<const ushort4a*>(&s_hi[arow * HSTR + 16 + 4 * g]);
      short8_t hi8;
#pragma unroll
      for (int e = 0; e < 4; ++e) {
        hi8[e] = (short)u0[e];
        hi8[e + 4] = (short)u1[e];
      }
      ah[k] = hi8;
    }

    f32x4 accv[2];
#pragma unroll
    for (int nt = 0; nt < 2; ++nt) {
      const float cb = nt ? cb1 : cb0;
      f32x4 acc = {cb, cb, cb, cb};
#pragma unroll
      for (int k = 0; k < 3; ++k) {
        acc = __builtin_amdgcn_mfma_f32_16x16x32_bf16(ah[k], bch[k][nt], acc, 0, 0, 0);
        acc = __builtin_amdgcn_mfma_f32_16x16x32_bf16(ah[k], bcl[k][nt], acc, 0, 0, 0);
      }
      accv[nt] = acc;
    }

    // ---- wide-store epilogue: transpose acc through wave-private LDS ----
    WAVE_FENCE();   // WAR: previous m-tile's staging reads retired
#pragma unroll
    for (int nt = 0; nt < 2; ++nt)
#pragma unroll
      for (int q = 0; q < 4; ++q)
        st[(4 * g + q) * SSTR + r + 16 * nt] = accv[nt][q];
    WAVE_FENCE();   // RAW: staging writes visible to transposed reads

#pragma unroll
    for (int h2 = 0; h2 < 2; ++h2) {
      const int row = h2 * 8 + (l >> 3);          // 8-lane groups read one row
      const float* rp = st + row * SSTR + (l & 7) * 4;
      const f32x2 rd0 = *reinterpret_cast<const f32x2*>(rp);      // 8B reads keep
      const f32x2 rd1 = *reinterpret_cast<const f32x2*>(rp + 2);  // odd rows aligned
      f32x4 rd;
      rd[0] = rd0[0]; rd[1] = rd0[1]; rd[2] = rd1[0]; rd[3] = rd1[1];
      const int t = t0 + m0 + row;
      // Nontemporal: out is write-once; do not evict the L2-resident x columns.
      __builtin_nontemporal_store(rd, reinterpret_cast<f32x4*>(
          out + ((size_t)(b * T + t) * NJ + j) * 32 + (l & 7) * 4));
    }
  }
}

extern "C" void kernel_launch(void* const* d_in, const int* in_sizes, int n_in,
                              void* d_out, int out_size, void* d_ws, size_t ws_size,
                              hipStream_t stream) {
  const float* x      = (const float*)d_in[0];
  const float* lin_w  = (const float*)d_in[1];
  const float* lin_b  = (const float*)d_in[2];
  const float* conv_w = (const float*)d_in[3];
  const float* conv_b = (const float*)d_in[4];
  float* out = (float*)d_out;

  prep_weights<<<dim3(NN), 64, 0, stream>>>(lin_w, conv_w);
  fused_rcb_mfma<<<dim3(NBLK), 256, 0, stream>>>(x, lin_b, conv_b, out);
}

// Round 4
// 77.677 us; speedup vs baseline: 2.2786x; 1.1483x over previous
//
#include <hip/hip_runtime.h>
#include <hip/hip_bf16.h>
#include <cstddef>
#include <cstdint>

typedef __attribute__((ext_vector_type(8))) short short8_t;   // 8 bf16 (4 VGPRs)
typedef __attribute__((ext_vector_type(4))) float f32x4;
typedef __attribute__((ext_vector_type(2))) float f32x2;
typedef unsigned short ushort4a __attribute__((ext_vector_type(4))); // 8B

// Per-wave fences (R10/R12-proven): forbid compiler motion of memory ops and
// drain the relevant HW queue. Cross-lane LDS deps and LDS-DMA writes are
// invisible to per-thread dependence analysis.
#define WAVE_FENCE()                                        \
  do {                                                      \
    asm volatile("s_waitcnt lgkmcnt(0)" ::: "memory");      \
    __builtin_amdgcn_sched_barrier(0);                      \
  } while (0)
#define VM_FENCE()                                          \
  do {                                                      \
    asm volatile("s_waitcnt vmcnt(0)" ::: "memory");        \
    __builtin_amdgcn_sched_barrier(0);                      \
  } while (0)

namespace {
constexpr int T = 2048;
constexpr int NB = 16;
constexpr int NJ = 53;
constexpr int NN = 18;              // names
// R16: TTILE back to 256. R12->R13 confounded TTILE=128 with NT stores; the
// NT-store mechanism (write-once out no longer evicting x from L2) plausibly
// explains the FETCH collapse alone. TTILE=256 halves the per-block
// fixed tax (weight-load prologue drain, non-steady-state lin pipeline,
// barrier count): 27 rounds/CU instead of 53. LDS 34.9KB -> still 4 blocks/CU.
constexpr int TTILE = 256;
constexpr int NTILES = T / TTILE;   // 8
constexpr int MT_LIN = 17;          // ceil(258/16) m-tiles for linear phase
constexpr int MT_CNV = 16;          // conv m-tiles
constexpr int HROWS = TTILE + 2;    // 258 h rows actually consumed by conv
constexpr int HSTR = 36;            // ushort stride per h row (72B, 8B-aligned rows)
// R15: SSTR=38. 40 gave g-stride 160 dwords == 0 mod 32 -> every staging
// write 4-way conflicted. 152 == 24 mod 32 -> writes 2-way (free). Reads
// split to 8B so odd rows stay aligned.
constexpr int SSTR = 38;            // f32 stride of store-staging tile (152B)
constexpr int NBLK = NB * NJ * NTILES;  // 6784
constexpr int XSPAN = NBLK / 8;         // 848 (bijective XCD swizzle)
}

__constant__ int c_name_ids[NJ] = {
    0,1,2,3,4,1,2,3,4,5,6,7,8,9,10,11,12,13,14,15,16,14,15,16,14,15,16,
    14,15,16,14,15,16,10,11,12,13,14,15,16,14,15,16,14,15,16,14,15,16,
    14,15,16,17};

// Precomputed weight fragments: [name][ks|k][nt][hi/lo][lane]
__device__ short8_t g_linfrag[NN][2][2][2][64];   // 147 KB
__device__ short8_t g_convfrag[NN][3][2][2][64];  // 221 KB

__device__ __forceinline__ unsigned short f2bf(float f) {
  return __builtin_bit_cast(unsigned short, __float2bfloat16(f));
}
__device__ __forceinline__ float bf2f(unsigned short u) {
  return __bfloat162float(__builtin_bit_cast(__hip_bfloat16, u));
}

// slot map: slot(g,e) -> k = 4g + (e&3) + 16*(e>>2); used identically for A and B
// fragments, so any true HW k-map yields a correct dot product.

__global__ __launch_bounds__(64)
void prep_weights(const float* __restrict__ lin_w,
                  const float* __restrict__ conv_w)
{
  const int n = blockIdx.x;
  const int l = threadIdx.x;
  const int r = l & 15;
  const int g = l >> 4;
#pragma unroll
  for (int ks = 0; ks < 2; ++ks)
#pragma unroll
    for (int nt = 0; nt < 2; ++nt) {
      short8_t hi8, lo8;
#pragma unroll
      for (int e = 0; e < 8; ++e) {
        const int kk = 4 * g + (e & 3) + 16 * (e >> 2);
        const float w = lin_w[((size_t)n * 64 + ks * 32 + kk) * 32 + r + 16 * nt];
        const unsigned short h = f2bf(w);
        hi8[e] = (short)h;
        lo8[e] = (short)f2bf(w - bf2f(h));
      }
      g_linfrag[n][ks][nt][0][l] = hi8;
      g_linfrag[n][ks][nt][1][l] = lo8;
    }
#pragma unroll
  for (int k = 0; k < 3; ++k)
#pragma unroll
    for (int nt = 0; nt < 2; ++nt) {
      short8_t hi8, lo8;
#pragma unroll
      for (int e = 0; e < 8; ++e) {
        const int i = 4 * g + (e & 3) + 16 * (e >> 2);
        const float w = conv_w[(((size_t)n * 32 + r + 16 * nt) * 32 + i) * 3 + k];
        const unsigned short h = f2bf(w);
        hi8[e] = (short)h;
        lo8[e] = (short)f2bf(w - bf2f(h));
      }
      g_convfrag[n][k][nt][0][l] = hi8;
      g_convfrag[n][k][nt][1][l] = lo8;
    }
}

// R16 = R15 structure with TTILE=256 (single-variable experiment). R15 kept:
//   - LDS-DMA staging, launch_bounds(256,4) (R14's (256,7) -> spills)
//   - SSTR=38 staging bank fix
//   - RTZ hi/lo split (bit-ops only) in the hot cvt loop
//   - DMA issue directly after fragment ds_reads retire
//   - conv-weight fragment loads before __syncthreads
__global__ __launch_bounds__(256, 4)
void fused_rcb_mfma(const float* __restrict__ x,
                    const float* __restrict__ lin_b,
                    const float* __restrict__ conv_b,
                    float* __restrict__ out)
{
  __shared__ __align__(16) unsigned short s_hi[HROWS * HSTR];  // 18.6 KB
  __shared__ __align__(16) char s_feat[4][4096];               // 16 KB: feat stage (lin) / store stage (conv)

  const int raw = blockIdx.x;
  const int bid = (raw % 8) * XSPAN + (raw / 8);   // bijective XCD swizzle
  const int j    = bid % NJ;
  const int tile = (bid / NJ) % NTILES;
  const int b    = bid / (NJ * NTILES);
  const int nid  = c_name_ids[j];
  const int jp   = (j > 0) ? (j - 1) : 0;
  const int t0   = tile * TTILE;

  const int tid = threadIdx.x;
  const int wv = tid >> 6;        // wave 0..3
  const int l  = tid & 63;
  const int r  = l & 15;          // M/N index within fragment
  const int g  = l >> 4;          // k-slot group

  char* featc = s_feat[wv];       // wave-private

  const float* xj_base = x + ((size_t)b * T * NJ + j) * 32;
  const float* xp_base = x + ((size_t)b * T * NJ + jp) * 32;

  // ---- linear weight fragments: coalesced 16B/lane loads from prep table ----
  short8_t blh[2][2], bll[2][2];
#pragma unroll
  for (int ks = 0; ks < 2; ++ks)
#pragma unroll
    for (int nt = 0; nt < 2; ++nt) {
      blh[ks][nt] = g_linfrag[nid][ks][nt][0][l];
      bll[ks][nt] = g_linfrag[nid][ks][nt][1][l];
    }
  const float lb0 = lin_b[nid * 32 + r];
  const float lb1 = lin_b[nid * 32 + r + 16];

  // Issue the 4 LDS-DMA loads for m-tile mt: 2 j x 2 groups of 8 rows, each
  // instruction a contiguous 1KB (8 full lines). Global source byte is
  // inverse-XOR-swizzled so LDS holds the swizzled layout (rule #21).
  auto issue_feat = [&](int mt) {
#pragma unroll
    for (int j2 = 0; j2 < 2; ++j2) {
      const float* jb = j2 ? xp_base : xj_base;
#pragma unroll
      for (int i = 0; i < 2; ++i) {
        const int row = i * 8 + (l >> 3);
        int t = t0 + mt * 16 + row - 1;       // reflect padding in time
        if (t < 0) t = -t;
        if (t > T - 1) t = 2 * (T - 1) - t;
        const char* src = reinterpret_cast<const char*>(jb + (size_t)t * (NJ * 32))
                          + (((l & 7) * 16) ^ ((row & 7) << 4));
        __builtin_amdgcn_global_load_lds(
            (const __attribute__((address_space(1))) unsigned int*)src,
            (__attribute__((address_space(3))) unsigned int*)(&s_feat[wv][j2 * 2048 + i * 1024]),
            16, 0, 0);
      }
    }
  };

  // ---------------- linear phase: h = relu(feat @ W + b) ----------------
  issue_feat(wv);
  for (int mt = wv; mt < MT_LIN; mt += 4) {
    VM_FENCE();   // feat[mt] fully landed in LDS (LDS-DMA tracked by vmcnt)

    // Fragment ds_reads first; cvt deferred until after next DMA is issued so
    // the DMA overlaps the cvt chain AND the MFMA block.
    f32x4 a0[2], a1[2];
#pragma unroll
    for (int ks = 0; ks < 2; ++ks) {
      const char* fw = featc + ks * 2048 + r * 128;
      a0[ks] = *reinterpret_cast<const f32x4*>(fw + ((16 * g) ^ ((r & 7) << 4)));
      a1[ks] = *reinterpret_cast<const f32x4*>(fw + ((64 + 16 * g) ^ ((r & 7) << 4)));
    }
    WAVE_FENCE();                       // feat reads retired -> buffer reusable
    if (mt + 4 < MT_LIN) issue_feat(mt + 4);   // DMA overlaps cvt + MFMA below

    short8_t ah[2], al[2];
#pragma unroll
    for (int ks = 0; ks < 2; ++ks) {
#pragma unroll
      for (int e = 0; e < 8; ++e) {
        const float f = (e < 4) ? a0[ks][e] : a1[ks][e - 4];
        const uint32_t bi = __builtin_bit_cast(uint32_t, f);
        ah[ks][e] = (short)(unsigned short)(bi >> 16);                    // hi = RTZ top16
        const float lo = f - __builtin_bit_cast(float, bi & 0xffff0000u); // exact residual
        al[ks][e] = (short)(unsigned short)(__builtin_bit_cast(uint32_t, lo) >> 16); // RTZ
      }
    }

#pragma unroll
    for (int nt = 0; nt < 2; ++nt) {
      const float lb = nt ? lb1 : lb0;
      f32x4 acc = {lb, lb, lb, lb};
#pragma unroll
      for (int ks = 0; ks < 2; ++ks) {
        acc = __builtin_amdgcn_mfma_f32_16x16x32_bf16(ah[ks], blh[ks][nt], acc, 0, 0, 0);
        acc = __builtin_amdgcn_mfma_f32_16x16x32_bf16(al[ks], blh[ks][nt], acc, 0, 0, 0);
        acc = __builtin_amdgcn_mfma_f32_16x16x32_bf16(ah[ks], bll[ks][nt], acc, 0, 0, 0);
      }
      // C/D layout (m89): row = 4g+q, col = r
#pragma unroll
      for (int q = 0; q < 4; ++q) {
        const int hrow = mt * 16 + 4 * g + q;
        if (hrow < HROWS)   // only mt=16 tail rows are out of range
          s_hi[hrow * HSTR + r + 16 * nt] = f2bf(fmaxf(acc[q], 0.0f));
      }
    }
  }

  // ---- conv weight fragments: issue BEFORE the barrier so the global-load
  // latency hides under the slowest wave's lin tail ----
  short8_t bch[3][2], bcl[3][2];
#pragma unroll
  for (int k = 0; k < 3; ++k)
#pragma unroll
    for (int nt = 0; nt < 2; ++nt) {
      bch[k][nt] = g_convfrag[nid][k][nt][0][l];
      bcl[k][nt] = g_convfrag[nid][k][nt][1][l];
    }
  const float cb0 = conv_b[nid * 32 + r];
  const float cb1 = conv_b[nid * 32 + r + 16];

  __syncthreads();

  float* st = reinterpret_cast<float*>(featc);   // alias: feat buffer dead in conv

  // ---------------- conv phase: y[t] = sum_k h[t+k-1] @ cw[k] + cb ----------------
  for (int mt = wv; mt < MT_CNV; mt += 4) {
    const int m0 = mt * 16;
    short8_t ah[3];
#pragma unroll
    for (int k = 0; k < 3; ++k) {
      const int arow = m0 + r + k;
      const ushort4a u0 = *reinterpret_cast<const ushort4a*>(&s_hi[arow * HSTR + 4 * g]);
      const ushort4a u1 = *reinterpret_cast<const ushort4a*>(&s_hi[arow * HSTR + 16 + 4 * g]);
      short8_t hi8;
#pragma unroll
      for (int e = 0; e < 4; ++e) {
        hi8[e] = (short)u0[e];
        hi8[e + 4] = (short)u1[e];
      }
      ah[k] = hi8;
    }

    f32x4 accv[2];
#pragma unroll
    for (int nt = 0; nt < 2; ++nt) {
      const float cb = nt ? cb1 : cb0;
      f32x4 acc = {cb, cb, cb, cb};
#pragma unroll
      for (int k = 0; k < 3; ++k) {
        acc = __builtin_amdgcn_mfma_f32_16x16x32_bf16(ah[k], bch[k][nt], acc, 0, 0, 0);
        acc = __builtin_amdgcn_mfma_f32_16x16x32_bf16(ah[k], bcl[k][nt], acc, 0, 0, 0);
      }
      accv[nt] = acc;
    }

    // ---- wide-store epilogue: transpose acc through wave-private LDS ----
    WAVE_FENCE();   // WAR: previous m-tile's staging reads retired
#pragma unroll
    for (int nt = 0; nt < 2; ++nt)
#pragma unroll
      for (int q = 0; q < 4; ++q)
        st[(4 * g + q) * SSTR + r + 16 * nt] = accv[nt][q];
    WAVE_FENCE();   // RAW: staging writes visible to transposed reads

#pragma unroll
    for (int h2 = 0; h2 < 2; ++h2) {
      const int row = h2 * 8 + (l >> 3);          // 8-lane groups read one row
      const float* rp = st + row * SSTR + (l & 7) * 4;
      const f32x2 rd0 = *reinterpret_cast<const f32x2*>(rp);      // 8B reads keep
      const f32x2 rd1 = *reinterpret_cast<const f32x2*>(rp + 2);  // odd rows aligned
      f32x4 rd;
      rd[0] = rd0[0]; rd[1] = rd0[1]; rd[2] = rd1[0]; rd[3] = rd1[1];
      const int t = t0 + m0 + row;
      // Nontemporal: out is write-once; do not evict the L2-resident x columns.
      __builtin_nontemporal_store(rd, reinterpret_cast<f32x4*>(
          out + ((size_t)(b * T + t) * NJ + j) * 32 + (l & 7) * 4));
    }
  }
}

extern "C" void kernel_launch(void* const* d_in, const int* in_sizes, int n_in,
                              void* d_out, int out_size, void* d_ws, size_t ws_size,
                              hipStream_t stream) {
  const float* x      = (const float*)d_in[0];
  const float* lin_w  = (const float*)d_in[1];
  const float* lin_b  = (const float*)d_in[2];
  const float* conv_w = (const float*)d_in[3];
  const float* conv_b = (const float*)d_in[4];
  float* out = (float*)d_out;

  prep_weights<<<dim3(NN), 64, 0, stream>>>(lin_w, conv_w);
  fused_rcb_mfma<<<dim3(NBLK), 256, 0, stream>>>(x, lin_b, conv_b, out);
}